// Round 1
// 402.511 us; speedup vs baseline: 1.0303x; 1.0303x over previous
//
#include <hip/hip_runtime.h>
#include <hip/hip_bf16.h>
#include <hip/hip_fp16.h>
#include <type_traits>

#define NNODES 100000
#define NEDGES 800000
#define HIDDIM 128
#define NHEAD 4

// bucket sort parameters
#define EPB 2048                 // edges per chunk-block (was 8192: 4x more blocks for occupancy)
#define NBLK 392                 // padded to 8*49 so XCD swizzle is exact; chunk 391 is empty
#define XCDG 49                  // NBLK / 8 — contiguous chunks per XCD
#define BSH 7                    // 128 nodes per bucket
#define NBUCK 782                // ceil(NNODES / 128); last bucket has 32 nodes

typedef _Float16 half8 __attribute__((ext_vector_type(8)));
typedef _Float16 half2t __attribute__((ext_vector_type(2)));
typedef float floatx4 __attribute__((ext_vector_type(4)));

// ---------------- CSR build via bucket counting-sort (no global atomics) ----------------

// Phase A: per-(chunk, bucket) histogram in LDS, non-atomic global write.
__global__ __launch_bounds__(256) void bucketA_k(const int* __restrict__ e0,
                                                 const int* __restrict__ e1,
                                                 const int* __restrict__ e2,
                                                 int* __restrict__ counts) {
    __shared__ int hist[NBUCK];
    int l = blockIdx.y;
    const int* dst = ((l == 0) ? e0 : (l == 1) ? e1 : e2) + NEDGES;
    int j = blockIdx.x;
    for (int t = threadIdx.x; t < NBUCK; t += 256) hist[t] = 0;
    __syncthreads();
    int base = j * EPB;
    int lim = min(EPB, NEDGES - base);
    if (lim == EPB) {
        #pragma unroll
        for (int it = 0; it < EPB / 256; it++)
            atomicAdd(&hist[dst[base + it * 256 + threadIdx.x] >> BSH], 1);
    } else {
        for (int i = threadIdx.x; i < lim; i += 256)
            atomicAdd(&hist[dst[base + i] >> BSH], 1);
    }
    __syncthreads();
    int* crow = counts + ((size_t)l * NBLK + j) * NBUCK;
    for (int t = threadIdx.x; t < NBUCK; t += 256) crow[t] = hist[t];
}

// Phase B1: per-bucket exclusive scan over the 392 chunk counts (in place) + bucket totals.
// One bucket per LANE (64 consecutive buckets per block -> coalesced 256B rows);
// 4 waves each own a 98-chunk quarter; wave partials combined via LDS.
__global__ __launch_bounds__(256) void bucketB1_k(int* __restrict__ counts,
                                                  int* __restrict__ bucketTotal) {
    __shared__ int part[4][64];
    int l = blockIdx.y;
    int tid = threadIdx.x;
    int wave = tid >> 6;
    int lane = tid & 63;
    int b = blockIdx.x * 64 + lane;
    bool valid = b < NBUCK;
    const int CQ = NBLK / 4;  // 98 chunks per wave
    int t0 = wave * CQ, t1 = t0 + CQ;
    int sum = 0;
    if (valid) {
        for (int t = t0; t < t1; t++)
            sum += counts[((size_t)l * NBLK + t) * NBUCK + b];
    }
    part[wave][lane] = sum;
    __syncthreads();
    int off = 0;
    for (int w = 0; w < wave; w++) off += part[w][lane];
    if (valid) {
        int run = off;
        for (int t = t0; t < t1; t++) {
            size_t idx = ((size_t)l * NBLK + t) * NBUCK + b;
            int v = counts[idx];
            counts[idx] = run;  // exclusive prefix
            run += v;
        }
        if (wave == 3) bucketTotal[l * NBUCK + b] = run;  // total over all chunks
    }
}

// Phase B2: per-layer exclusive scans over buckets: edgeBuf bases (raw totals)
// and CSR bases (totals + nodes-in-bucket for self-loop slots).
__global__ __launch_bounds__(1024) void bucketB2_k(const int* __restrict__ bucketTotal,
                                                   int* __restrict__ ebBase,
                                                   int* __restrict__ csrBase) {
    __shared__ int sd[1024];
    int l = blockIdx.x;
    int t = threadIdx.x;
    int tot = (t < NBUCK) ? bucketTotal[l * NBUCK + t] : 0;
    sd[t] = tot;
    __syncthreads();
    for (int off = 1; off < 1024; off <<= 1) {
        int u = (t >= off) ? sd[t - off] : 0;
        __syncthreads();
        sd[t] += u;
        __syncthreads();
    }
    if (t < NBUCK) ebBase[l * NBUCK + t] = sd[t] - tot;
    __syncthreads();
    int nb = (t == NBUCK - 1) ? (NNODES - (NBUCK - 1) * 128) : 128;
    int v2 = (t < NBUCK) ? (tot + nb) : 0;
    sd[t] = v2;
    __syncthreads();
    for (int off = 1; off < 1024; off <<= 1) {
        int u = (t >= off) ? sd[t - off] : 0;
        __syncthreads();
        sd[t] += u;
        __syncthreads();
    }
    if (t < NBUCK) csrBase[l * NBUCK + t] = sd[t] - v2;
}

// Phase C: scatter edges into bucket-grouped edgeBuf, packed (dstLocal<<17)|src.
// Cursors live in LDS (per-block disjoint sub-ranges; LDS atomics only).
// XCD swizzle: consecutive chunks -> same XCD, so adjacent sub-ranges of each
// bucket region share one L2 and partial 64B lines merge before writeback.
__global__ __launch_bounds__(256) void bucketC_k(const int* __restrict__ e0,
                                                 const int* __restrict__ e1,
                                                 const int* __restrict__ e2,
                                                 const int* __restrict__ counts,
                                                 const int* __restrict__ ebBase,
                                                 int* __restrict__ edgeBuf) {
    __shared__ int cur[NBUCK];
    int l = blockIdx.y;
    const int* ei = (l == 0) ? e0 : (l == 1) ? e1 : e2;
    const int* src = ei;
    const int* dst = ei + NEDGES;
    int bx = blockIdx.x;
    int j = (bx & 7) * XCDG + (bx >> 3);  // XCD-contiguous chunk groups
    const int* bs = counts + ((size_t)l * NBLK + j) * NBUCK;
    const int* eb = ebBase + l * NBUCK;
    for (int t = threadIdx.x; t < NBUCK; t += 256) cur[t] = eb[t] + bs[t];
    __syncthreads();
    int base = j * EPB;
    int lim = min(EPB, NEDGES - base);
    int* ebuf = edgeBuf + (size_t)l * NEDGES;
    if (lim == EPB) {
        #pragma unroll
        for (int it = 0; it < EPB / 256; it++) {
            int i = it * 256 + threadIdx.x;
            int d = dst[base + i];
            int s = src[base + i];
            int pos = atomicAdd(&cur[d >> BSH], 1);
            ebuf[pos] = ((d & 127) << 17) | s;
        }
    } else {
        for (int i = threadIdx.x; i < lim; i += 256) {
            int d = dst[base + i];
            int s = src[base + i];
            int pos = atomicAdd(&cur[d >> BSH], 1);
            ebuf[pos] = ((d & 127) << 17) | s;
        }
    }
}

// Phase D: one block per bucket: per-node counts, wave-shuffle scan, write
// offs/deg, scatter srcs + self-loops. Single-block ownership of the region.
__global__ __launch_bounds__(256) void bucketD_k(const int* __restrict__ edgeBuf,
                                                 const int* __restrict__ bucketTotal,
                                                 const int* __restrict__ ebBase,
                                                 const int* __restrict__ csrBase,
                                                 int* __restrict__ offs,
                                                 int* __restrict__ deg,
                                                 int* __restrict__ srcs) {
    __shared__ int cnt[128];
    __shared__ int offl[128];
    __shared__ int cur[128];
    int b = blockIdx.x, l = blockIdx.y;
    int t = threadIdx.x;
    int nb = (b == NBUCK - 1) ? (NNODES - (NBUCK - 1) * 128) : 128;
    int eb0 = ebBase[l * NBUCK + b];
    int ecnt = bucketTotal[l * NBUCK + b];
    int csr0 = csrBase[l * NBUCK + b];
    const int* ebuf = edgeBuf + (size_t)l * NEDGES;
    int* srcsL = srcs + (size_t)l * (NEDGES + NNODES);
    if (t < 128) cnt[t] = 0;
    __syncthreads();
    for (int i = t; i < ecnt; i += 256)
        atomicAdd(&cnt[ebuf[eb0 + i] >> 17], 1);
    __syncthreads();
    if (t < 128) {
        int lane = t & 63;
        int x = cnt[t] + 1;  // +1 self-loop slot (pad nodes harmless: trail real nodes)
        #pragma unroll
        for (int o = 1; o < 64; o <<= 1) {
            int u = __shfl_up(x, o);
            if (lane >= o) x += u;
        }
        offl[t] = x;  // inclusive within wave
    }
    __syncthreads();
    if (t < 128) {
        int c = cnt[t];
        int incl = offl[t] + ((t >= 64) ? offl[63] : 0);
        int o = csr0 + incl - (c + 1);  // exclusive
        cur[t] = o;
        if (t < nb) {
            int node = b * 128 + t;
            offs[l * NNODES + node] = o;
            deg[l * NNODES + node] = c;
            srcsL[o + c] = node;  // self-loop in last slot
        }
    }
    __syncthreads();
    for (int i = t; i < ecnt; i += 256) {
        int w = ebuf[eb0 + i];
        int pos = atomicAdd(&cur[w >> 17], 1);
        srcsL[pos] = w & 0x1FFFF;
    }
}

// ---------------- GEMM + attention logits via extended-N MFMA ----------------
// h16[M,128] = fp16(A @ B); aSD[M,8] = logits (col j = head*2 + {0:src,1:dst}).
// (x@W)·att == x·(W@att): appended columns 128..135 hold Wa = W @ att_masked.

template <typename AT>
__global__ __launch_bounds__(256, 2) void gemm_mfma_k(const AT* __restrict__ A,
                                                      const float* __restrict__ B,
                                                      const float* __restrict__ attS,
                                                      const float* __restrict__ attD,
                                                      __half* __restrict__ C16,
                                                      float* __restrict__ aSD, int M) {
    __shared__ __half Bt[144 * 136];  // Bt[n][k]; rows 128..135 Wa cols, 136..143 zero
    const int tid = threadIdx.x;
    {   // stage B transposed as fp16 (rows 0..127)
        int kk = (tid & 63) * 2;
        int g = tid >> 6;
        #pragma unroll
        for (int jn = 0; jn < 8; jn++) {
            int n0 = g * 4 + jn * 16;
            float4 r0 = *(const float4*)(B + (size_t)kk * 128 + n0);
            float4 r1 = *(const float4*)(B + (size_t)(kk + 1) * 128 + n0);
            float f0[4] = {r0.x, r0.y, r0.z, r0.w};
            float f1[4] = {r1.x, r1.y, r1.z, r1.w};
            #pragma unroll
            for (int i = 0; i < 4; i++)
                *(__half2*)(&Bt[(n0 + i) * 136 + kk]) = __floats2half2_rn(f0[i], f1[i]);
        }
    }
    if (tid < 128) {  // Wa columns (rows 128..135), fp32 accumulate
        int k = tid;
        const float* Brow = B + (size_t)k * 128;
        #pragma unroll
        for (int h = 0; h < NHEAD; h++) {
            float s0 = 0.f, s1 = 0.f;
            #pragma unroll 8
            for (int c = 0; c < 32; c++) {
                float bb = Brow[h * 32 + c];
                s0 += bb * attS[h * 32 + c];
                s1 += bb * attD[h * 32 + c];
            }
            Bt[(128 + h * 2 + 0) * 136 + k] = (_Float16)s0;
            Bt[(128 + h * 2 + 1) * 136 + k] = (_Float16)s1;
        }
    } else {
        int k = tid - 128;
        #pragma unroll
        for (int j = 8; j < 16; j++) Bt[(128 + j) * 136 + k] = (_Float16)0.f;
    }
    __syncthreads();

    const int lane = tid & 63;
    const int wave = tid >> 6;
    const int m = lane & 15;
    const int q = lane >> 4;

    half8 bfrag[9][4];
    #pragma unroll
    for (int c = 0; c < 9; c++)
        #pragma unroll
        for (int t = 0; t < 4; t++)
            bfrag[c][t] = *(const half8*)(&Bt[(c * 16 + m) * 136 + t * 32 + q * 8]);

    for (int iter = 0; iter < 4; iter++) {
        int rb = blockIdx.x * 256 + iter * 64 + wave * 16;  // wave-uniform
        if (rb >= M) break;
        int row = rb + m;
        int rowc = row < M ? row : M - 1;
        half8 a[4];
        if constexpr (std::is_same<AT, __half>::value) {
            const __half* ap = A + (size_t)rowc * HIDDIM;
            #pragma unroll
            for (int t = 0; t < 4; t++)
                a[t] = *(const half8*)(ap + t * 32 + q * 8);
        } else {
            const float* ap = A + (size_t)rowc * HIDDIM;
            #pragma unroll
            for (int t = 0; t < 4; t++) {
                float4 u = *(const float4*)(ap + t * 32 + q * 8);
                float4 v = *(const float4*)(ap + t * 32 + q * 8 + 4);
                half8 h;
                h[0] = (_Float16)u.x; h[1] = (_Float16)u.y;
                h[2] = (_Float16)u.z; h[3] = (_Float16)u.w;
                h[4] = (_Float16)v.x; h[5] = (_Float16)v.y;
                h[6] = (_Float16)v.z; h[7] = (_Float16)v.w;
                a[t] = h;
            }
        }
        floatx4 acc[9];
        #pragma unroll
        for (int c = 0; c < 9; c++) acc[c] = (floatx4){0.f, 0.f, 0.f, 0.f};
        #pragma unroll
        for (int t = 0; t < 4; t++)
            #pragma unroll
            for (int c = 0; c < 9; c++)
                acc[c] = __builtin_amdgcn_mfma_f32_16x16x32_f16(a[t], bfrag[c][t], acc[c], 0, 0, 0);
        #pragma unroll
        for (int c = 0; c < 8; c++)
            #pragma unroll
            for (int r = 0; r < 4; r++) {
                int grow = rb + q * 4 + r;
                if (grow < M)
                    C16[(size_t)grow * HIDDIM + c * 16 + m] = __float2half(acc[c][r]);
            }
        if (m < 8) {
            #pragma unroll
            for (int r = 0; r < 4; r++) {
                int grow = rb + q * 4 + r;
                if (grow < M) aSD[(size_t)grow * 8 + m] = acc[8][r];
            }
        }
    }
}

// ---------------- aggregate: one 16-lane group per node, 2-deep pipeline ----------------

template <bool HALF_OUT>
__global__ __launch_bounds__(256) void agg_k(const __half* __restrict__ h16,
                                             const int* __restrict__ offs,
                                             const int* __restrict__ deg,
                                             const int* __restrict__ srcs,
                                             const float* __restrict__ aSD,
                                             const float* __restrict__ bias,
                                             void* __restrict__ outv) {
    int tid = threadIdx.x;
    int lane = tid & 63;
    int grp = lane >> 4;      // node group within wave (0..3)
    int cg = lane & 15;       // channel group within node
    int c8 = cg * 8;
    int h2 = (cg >> 2) * 2;   // head*2
    int n = blockIdx.x * 16 + (tid >> 6) * 4 + grp;
    bool nvalid = n < NNODES;
    int nn = nvalid ? n : NNODES - 1;
    int start = offs[nn];
    int cnt = deg[nn] + 1;
    float ad = aSD[(size_t)nn * 8 + h2 + 1];
    half2t acc0[4], acc1[4];
    #pragma unroll
    for (int i = 0; i < 4; i++) {
        acc0[i] = (half2t){(_Float16)0.f, (_Float16)0.f};
        acc1[i] = (half2t){(_Float16)0.f, (_Float16)0.f};
    }
    float wsum = 0.f;
    const int base = grp * 16;

    for (int chunk = 0; chunk < cnt; chunk += 16) {
        int idx = chunk + cg;
        int lim = min(16, cnt - chunk);
        int sv = srcs[start + (idx < cnt ? idx : cnt - 1)];  // clamped: always valid
        int s_a = __shfl(sv, base + 0);
        int s_b = __shfl(sv, base + 1);
        float as_a = aSD[(size_t)s_a * 8 + h2];
        float as_b = aSD[(size_t)s_b * 8 + h2];
        half8 hv_a = *(const half8*)(h16 + (size_t)s_a * HIDDIM + c8);
        half8 hv_b = *(const half8*)(h16 + (size_t)s_b * HIDDIM + c8);
        for (int j = 0; j < lim; j += 2) {
            int j2 = (j + 2 < 16) ? j + 2 : 15;
            int j3 = (j + 3 < 16) ? j + 3 : 15;
            int s_c = __shfl(sv, base + j2);
            int s_d = __shfl(sv, base + j3);
            float as_c = aSD[(size_t)s_c * 8 + h2];
            float as_d = aSD[(size_t)s_d * 8 + h2];
            half8 hv_c = *(const half8*)(h16 + (size_t)s_c * HIDDIM + c8);
            half8 hv_d = *(const half8*)(h16 + (size_t)s_d * HIDDIM + c8);

            float e0 = as_a + ad;
            e0 = (e0 > 0.f) ? e0 : 0.2f * e0;
            float w0 = __expf(e0);
            float e1 = as_b + ad;
            e1 = (e1 > 0.f) ? e1 : 0.2f * e1;
            float w1 = (j + 1 < lim) ? __expf(e1) : 0.f;
            wsum += w0 + w1;
            _Float16 w0h = (_Float16)w0, w1h = (_Float16)w1;
            half2t w02 = (half2t){w0h, w0h}, w12 = (half2t){w1h, w1h};
            #pragma unroll
            for (int i = 0; i < 4; i++) {
                acc0[i] += w02 * (half2t){hv_a[2 * i], hv_a[2 * i + 1]};
                acc1[i] += w12 * (half2t){hv_b[2 * i], hv_b[2 * i + 1]};
            }
            as_a = as_c; as_b = as_d;
            hv_a = hv_c; hv_b = hv_d;
        }
    }

    if (nvalid) {
        float inv = 1.f / (wsum + 1e-16f);
        float v[8];
        #pragma unroll
        for (int i = 0; i < 4; i++) {
            half2t s = acc0[i] + acc1[i];
            float o0 = (float)s[0] * inv + bias[c8 + 2 * i];
            float o1 = (float)s[1] * inv + bias[c8 + 2 * i + 1];
            v[2 * i] = o0 > 0.f ? o0 : 0.f;
            v[2 * i + 1] = o1 > 0.f ? o1 : 0.f;
        }
        if constexpr (HALF_OUT) {
            union { uint4 u; __half2 h2v[4]; } pk;
            #pragma unroll
            for (int i = 0; i < 4; i++) pk.h2v[i] = __floats2half2_rn(v[2 * i], v[2 * i + 1]);
            *(uint4*)((__half*)outv + (size_t)n * HIDDIM + c8) = pk.u;
        } else {
            float* out = (float*)outv;
            *(float4*)(out + (size_t)n * HIDDIM + c8) = make_float4(v[0], v[1], v[2], v[3]);
            *(float4*)(out + (size_t)n * HIDDIM + c8 + 4) = make_float4(v[4], v[5], v[6], v[7]);
        }
    }
}

// ---------------- launch ----------------

extern "C" void kernel_launch(void* const* d_in, const int* in_sizes, int n_in,
                              void* d_out, int out_size, void* d_ws, size_t ws_size,
                              hipStream_t stream) {
    (void)in_sizes; (void)n_in; (void)out_size; (void)ws_size;
    const float* x = (const float*)d_in[0];
    const int* e0 = (const int*)d_in[1];
    const int* e1 = (const int*)d_in[6];
    const int* e2 = (const int*)d_in[11];

    char* ws = (char*)d_ws;
    size_t off = 0;
    auto alloc = [&](size_t bytes) -> void* {
        void* p = ws + off;
        off += (bytes + 255) & ~(size_t)255;
        return p;
    };
    __half* xh      = (__half*)alloc((size_t)NNODES * HIDDIM * 2);
    __half* h16     = (__half*)alloc((size_t)NNODES * HIDDIM * 2);
    float* aSD      = (float*)alloc((size_t)NNODES * 8 * 4);
    int* deg        = (int*)alloc((size_t)3 * NNODES * 4);
    int* offsArr    = (int*)alloc((size_t)3 * NNODES * 4);
    int* srcs       = (int*)alloc((size_t)3 * (NEDGES + NNODES) * 4);
    int* counts     = (int*)alloc((size_t)3 * NBLK * NBUCK * 4);
    int* bucketTot  = (int*)alloc((size_t)3 * NBUCK * 4);
    int* ebBase     = (int*)alloc((size_t)3 * NBUCK * 4);
    int* csrBase    = (int*)alloc((size_t)3 * NBUCK * 4);
    int* edgeBuf    = (int*)alloc((size_t)3 * NEDGES * 4);

    // CSR build for all 3 layers — no global atomics
    hipLaunchKernelGGL(bucketA_k, dim3(NBLK, 3), dim3(256), 0, stream, e0, e1, e2, counts);
    hipLaunchKernelGGL(bucketB1_k, dim3((NBUCK + 63) / 64, 3), dim3(256), 0, stream,
                       counts, bucketTot);
    hipLaunchKernelGGL(bucketB2_k, dim3(3), dim3(1024), 0, stream, bucketTot, ebBase, csrBase);
    hipLaunchKernelGGL(bucketC_k, dim3(NBLK, 3), dim3(256), 0, stream,
                       e0, e1, e2, counts, ebBase, edgeBuf);
    hipLaunchKernelGGL(bucketD_k, dim3(NBUCK, 3), dim3(256), 0, stream,
                       edgeBuf, bucketTot, ebBase, csrBase, offsArr, deg, srcs);

    for (int l = 0; l < 3; l++) {
        const float* Wm    = (const float*)d_in[2 + 5 * l];
        const float* attS  = (const float*)d_in[3 + 5 * l];
        const float* attD  = (const float*)d_in[4 + 5 * l];
        const float* biasv = (const float*)d_in[5 + 5 * l];
        const int* offsL = offsArr + l * NNODES;
        const int* degL  = deg + l * NNODES;
        const int* srcsL = srcs + (size_t)l * (NEDGES + NNODES);

        if (l == 0) {
            hipLaunchKernelGGL((gemm_mfma_k<float>), dim3((NNODES + 255) / 256), dim3(256), 0,
                               stream, x, Wm, attS, attD, h16, aSD, NNODES);
        } else {
            hipLaunchKernelGGL((gemm_mfma_k<__half>), dim3((NNODES + 255) / 256), dim3(256), 0,
                               stream, xh, Wm, attS, attD, h16, aSD, NNODES);
        }
        if (l == 2) {
            hipLaunchKernelGGL((agg_k<false>), dim3((NNODES + 15) / 16), dim3(256), 0, stream,
                               h16, offsL, degL, srcsL, aSD, biasv, d_out);
        } else {
            hipLaunchKernelGGL((agg_k<true>), dim3((NNODES + 15) / 16), dim3(256), 0, stream,
                               h16, offsL, degL, srcsL, aSD, biasv, (void*)xh);
        }
    }
}